// Round 1
// baseline (833.345 us; speedup 1.0000x reference)
//
#include <hip/hip_runtime.h>

// HT layer: out[b] = (Σ_p A_p @ X[b] @ W_p) + bias
//   A_p[ac][ij]  = Σ_{r,s} F0[i,a,r] F1[j,c,s] CL[r,s,p]
//   W_pT[de][kl] = Σ_{r,s} F2[k,d,r] F3[l,e,s] CR[r,s,p]
//   X[b][ij][kl] = x[b][ij*64+kl], out[b][ac*64+de]

__global__ void ht_precompute(const float* __restrict__ F0, const float* __restrict__ F1,
                              const float* __restrict__ F2, const float* __restrict__ F3,
                              const float* __restrict__ CL, const float* __restrict__ CR,
                              float* __restrict__ A, float* __restrict__ WRT) {
    int idx = blockIdx.x * blockDim.x + threadIdx.x;   // 0..65535
    bool isA = idx < 32768;
    int t    = idx & 32767;
    int p    = t >> 12;          // 0..7
    int rowo = (t >> 6) & 63;    // ac or de
    int colo = t & 63;           // ij or kl
    int o1 = rowo >> 3, o2 = rowo & 7;   // a,c (or d,e)
    int i1 = colo >> 3, i2 = colo & 7;   // i,j (or k,l)
    const float* Fa = isA ? F0 : F2;
    const float* Fb = isA ? F1 : F3;
    const float* C  = isA ? CL : CR;
    float acc = 0.f;
    for (int r = 0; r < 8; ++r) {
        float fa = Fa[(i1 * 8 + o1) * 8 + r];
        for (int s = 0; s < 8; ++s) {
            acc += fa * Fb[(i2 * 8 + o2) * 8 + s] * C[(r * 8 + s) * 8 + p];
        }
    }
    float* dst = isA ? A : WRT;
    dst[(p * 64 + rowo) * 64 + colo] = acc;
}

__global__ __launch_bounds__(256) void ht_main(const float* __restrict__ x,
                                               const float* __restrict__ A,
                                               const float* __restrict__ WRT,
                                               const float* __restrict__ bias,
                                               float* __restrict__ out) {
    // T buffer, padded stride 65 to break 64-stride bank conflicts (2-way only = free)
    __shared__ float Tl[64 * 65];
    const int b    = blockIdx.x;
    const int tid  = threadIdx.x;
    const int lane = tid & 63;
    // wave id, forced scalar so weight addresses are provably wave-uniform -> s_load
    const int w = __builtin_amdgcn_readfirstlane(tid >> 6);

    // X column in VGPRs: xc[m] = x[b][m*64 + lane]  (lane = kl)
    float xc[64];
    const float* xb = x + (size_t)b * 4096 + lane;
#pragma unroll
    for (int m = 0; m < 64; ++m) xc[m] = xb[m * 64];

    float yacc[16];
#pragma unroll
    for (int i = 0; i < 16; ++i) yacc[i] = 0.f;

    float tc[64];

#pragma unroll 1
    for (int p = 0; p < 8; ++p) {
        // ---- Step A: T[r][kl] = sum_ij A_p[r][ij] * X[ij][kl]; wave w does rows 16w..16w+15
#pragma unroll
        for (int rr = 0; rr < 16; ++rr) {
            const int r = w * 16 + rr;
            const float* As = A + ((p << 6) + r) * 64;   // wave-uniform -> s_load
            float t0 = 0.f, t1 = 0.f, t2 = 0.f, t3 = 0.f;
#pragma unroll
            for (int m = 0; m < 64; m += 4) {
                t0 += As[m]     * xc[m];
                t1 += As[m + 1] * xc[m + 1];
                t2 += As[m + 2] * xc[m + 2];
                t3 += As[m + 3] * xc[m + 3];
            }
            Tl[r * 65 + lane] = (t0 + t1) + (t2 + t3);
        }
        __syncthreads();
        // T column into VGPRs: tc[kl] = T[lane][kl]  (lane = ac row)
#pragma unroll
        for (int kl = 0; kl < 64; ++kl) tc[kl] = Tl[lane * 65 + kl];
        // ---- Step B: Y[ac][de] += sum_kl T[ac][kl] * WRT_p[de][kl]; wave w does de 16w..16w+15
#pragma unroll
        for (int cc = 0; cc < 16; ++cc) {
            const int c = w * 16 + cc;
            const float* Ws = WRT + ((p << 6) + c) * 64;  // wave-uniform -> s_load
            float t0 = 0.f, t1 = 0.f, t2 = 0.f, t3 = 0.f;
#pragma unroll
            for (int kl = 0; kl < 64; kl += 4) {
                t0 += Ws[kl]     * tc[kl];
                t1 += Ws[kl + 1] * tc[kl + 1];
                t2 += Ws[kl + 2] * tc[kl + 2];
                t3 += Ws[kl + 3] * tc[kl + 3];
            }
            yacc[cc] += (t0 + t1) + (t2 + t3);
        }
        __syncthreads();
    }

    // ---- Epilogue: transpose Y via LDS, coalesced float4 stores with bias
#pragma unroll
    for (int cc = 0; cc < 16; ++cc) Tl[lane * 65 + w * 16 + cc] = yacc[cc];
    __syncthreads();
    const int r0 = tid >> 2;
    const int c0 = (tid & 3) * 16;
    float4* out4 = (float4*)(out + (size_t)b * 4096 + tid * 16);
    const float4* bias4 = (const float4*)(bias + tid * 16);
#pragma unroll
    for (int j = 0; j < 4; ++j) {
        float4 v;
        v.x = Tl[r0 * 65 + c0 + j * 4 + 0];
        v.y = Tl[r0 * 65 + c0 + j * 4 + 1];
        v.z = Tl[r0 * 65 + c0 + j * 4 + 2];
        v.w = Tl[r0 * 65 + c0 + j * 4 + 3];
        float4 bb = bias4[j];
        v.x += bb.x; v.y += bb.y; v.z += bb.z; v.w += bb.w;
        out4[j] = v;
    }
}

extern "C" void kernel_launch(void* const* d_in, const int* in_sizes, int n_in,
                              void* d_out, int out_size, void* d_ws, size_t ws_size,
                              hipStream_t stream) {
    const float* x    = (const float*)d_in[0];
    const float* F0   = (const float*)d_in[1];
    const float* F1   = (const float*)d_in[2];
    const float* F2   = (const float*)d_in[3];
    const float* F3   = (const float*)d_in[4];
    const float* CL   = (const float*)d_in[5];
    const float* CR   = (const float*)d_in[6];
    const float* bias = (const float*)d_in[7];
    float* out = (float*)d_out;

    float* A   = (float*)d_ws;          // 8*64*64 floats
    float* WRT = A + 8 * 64 * 64;       // 8*64*64 floats (256 KB total)

    const int B = in_sizes[0] / 4096;   // 4096

    ht_precompute<<<256, 256, 0, stream>>>(F0, F1, F2, F3, CL, CR, A, WRT);
    ht_main<<<B, 256, 0, stream>>>(x, A, WRT, bias, out);
}

// Round 2
// 153.758 us; speedup vs baseline: 5.4198x; 5.4198x over previous
//
#include <hip/hip_runtime.h>

// HT layer via bf16 MFMA, one wave per batch element.
//   Y[b] = sum_p A_p(64x64) @ X_b(64x64) @ W_p(64x64) + bias
// Step A: T^T[kl][ac] = sum_ij X^T[kl][ij] * A_p^T[ij][ac]   (M=kl,N=ac,K=ij)
// Step B: Y[ac][de]  += sum_kl T[ac][kl]  * W_p[kl][de]      (M=ac,N=de,K=kl)
// mfma_f32_16x16x32_bf16 layouts (m89/m120-verified):
//   A: A[m=lane&15][k=(lane>>4)*8+j]   B: B[k=(lane>>4)*8+j][n=lane&15]
//   C/D: col=lane&15, row=(lane>>4)*4+reg

typedef short bf16x8 __attribute__((ext_vector_type(8)));
typedef float f32x4  __attribute__((ext_vector_type(4)));

static __device__ __forceinline__ unsigned short f2bf(float f) {
    unsigned int u = __float_as_uint(f);
    u = (u + 0x7FFFu + ((u >> 16) & 1u)) >> 16;   // RNE
    return (unsigned short)u;
}

// Precompute bf16 B-operand fragments of A_p^T and W_p into ws.
// Layout: frags[isW][p(8)][f=cb*2+ks (8)][lane(64)][j(8)] bf16, 64KB each.
// Frag element: B[k = ks*32 + (lane>>4)*8 + j][n = cb*16 + (lane&15)]
__global__ void ht_precompute(const float* __restrict__ F0, const float* __restrict__ F1,
                              const float* __restrict__ F2, const float* __restrict__ F3,
                              const float* __restrict__ CL, const float* __restrict__ CR,
                              unsigned short* __restrict__ frags) {
    int idx = blockIdx.x * blockDim.x + threadIdx.x;   // 0..65535
    int isW = idx >> 15;
    int r15 = idx & 32767;
    int p    = r15 >> 12;
    int f    = (r15 >> 9) & 7;
    int lane = (r15 >> 3) & 63;
    int j    = r15 & 7;
    int cb = f >> 1, ks = f & 1;
    int n = cb * 16 + (lane & 15);            // ac or de
    int k = ks * 32 + ((lane >> 4) & 3) * 8 + j;  // ij or kl
    const float* Fa = isW ? F2 : F0;
    const float* Fb = isW ? F3 : F1;
    const float* C  = isW ? CR : CL;
    int i1 = k >> 3, i2 = k & 7, o1 = n >> 3, o2 = n & 7;
    float acc = 0.f;
    for (int r = 0; r < 8; ++r) {
        float fa = Fa[(i1 * 8 + o1) * 8 + r];
        for (int s = 0; s < 8; ++s)
            acc += fa * Fb[(i2 * 8 + o2) * 8 + s] * C[(r * 8 + s) * 8 + p];
    }
    frags[(size_t)isW * 32768 + ((p * 8 + f) << 9) + lane * 8 + j] = f2bf(acc);
}

__global__ __launch_bounds__(64) void ht_main(const float* __restrict__ x,
                                              const unsigned short* __restrict__ frags,
                                              const float* __restrict__ bias,
                                              float* __restrict__ out) {
    __shared__ unsigned short Tl[64 * 72];   // [ac][kl], pitch 72 bf16 (144B, 16B-aligned)
    const int b    = blockIdx.x;
    const int lane = threadIdx.x;            // one wave
    const int l15  = lane & 15;
    const int q    = lane >> 4;              // quad

    // X^T A-fragments: xf[rb][ks], element j = X^T[kl=rb*16+l15][ij=ks*32+q*8+j]
    bf16x8 xf[4][2];
    const float* xb = x + ((size_t)b << 12);
#pragma unroll
    for (int rb = 0; rb < 4; ++rb)
#pragma unroll
        for (int ks = 0; ks < 2; ++ks) {
            const float* src = xb + (ks * 32 + q * 8) * 64 + rb * 16 + l15;
#pragma unroll
            for (int j = 0; j < 8; ++j)
                xf[rb][ks][j] = (short)f2bf(src[j * 64]);
        }

    f32x4 acc[4][4];   // Y tiles: [rb over ac][cb over de]
#pragma unroll
    for (int i = 0; i < 4; ++i)
#pragma unroll
        for (int j = 0; j < 4; ++j)
            acc[i][j] = f32x4{0.f, 0.f, 0.f, 0.f};

    const unsigned short* AF = frags;          // A^T frags
    const unsigned short* WF = frags + 32768;  // W frags

#pragma unroll 1
    for (int p = 0; p < 8; ++p) {
        // ---- Step A: T^T = X^T @ A_p^T, write bf16 tiles to Tl[ac][kl]
        bf16x8 af[4][2];
#pragma unroll
        for (int cb = 0; cb < 4; ++cb)
#pragma unroll
            for (int ks = 0; ks < 2; ++ks)
                af[cb][ks] = *(const bf16x8*)(AF + (((p * 8 + cb * 2 + ks) << 9) + lane * 8));
#pragma unroll
        for (int rb = 0; rb < 4; ++rb) {       // rb: kl row-block
#pragma unroll
            for (int cb = 0; cb < 4; ++cb) {   // cb: ac col-block
                f32x4 t = f32x4{0.f, 0.f, 0.f, 0.f};
                t = __builtin_amdgcn_mfma_f32_16x16x32_bf16(xf[rb][0], af[cb][0], t, 0, 0, 0);
                t = __builtin_amdgcn_mfma_f32_16x16x32_bf16(xf[rb][1], af[cb][1], t, 0, 0, 0);
                // lane holds col ac=cb*16+l15, rows kl = rb*16+q*4+(0..3)
                int ac = cb * 16 + l15;
                int kl = rb * 16 + q * 4;
                ushort4 w;
                w.x = f2bf(t[0]); w.y = f2bf(t[1]); w.z = f2bf(t[2]); w.w = f2bf(t[3]);
                *(ushort4*)(&Tl[ac * 72 + kl]) = w;   // 8B store, aligned
            }
        }
        // ---- Step B: Y += T @ W_p  (same-wave LDS RAW: compiler inserts lgkmcnt)
        bf16x8 wf[4][2];
#pragma unroll
        for (int cb = 0; cb < 4; ++cb)
#pragma unroll
            for (int ks = 0; ks < 2; ++ks)
                wf[cb][ks] = *(const bf16x8*)(WF + (((p * 8 + cb * 2 + ks) << 9) + lane * 8));
        bf16x8 tf[4][2];
#pragma unroll
        for (int rb = 0; rb < 4; ++rb)
#pragma unroll
            for (int ks = 0; ks < 2; ++ks) {
                int ac = rb * 16 + l15;
                int kl = ks * 32 + q * 8;
                tf[rb][ks] = *(const bf16x8*)(&Tl[ac * 72 + kl]);   // 16B read, aligned
            }
#pragma unroll
        for (int rb = 0; rb < 4; ++rb)
#pragma unroll
            for (int cb = 0; cb < 4; ++cb) {
                acc[rb][cb] = __builtin_amdgcn_mfma_f32_16x16x32_bf16(tf[rb][0], wf[cb][0], acc[rb][cb], 0, 0, 0);
                acc[rb][cb] = __builtin_amdgcn_mfma_f32_16x16x32_bf16(tf[rb][1], wf[cb][1], acc[rb][cb], 0, 0, 0);
            }
    }

    // ---- Epilogue: bias + store (C/D: col de=cb*16+l15, rows ac=rb*16+q*4+r)
    float* ob = out + ((size_t)b << 12);
#pragma unroll
    for (int rb = 0; rb < 4; ++rb)
#pragma unroll
        for (int cb = 0; cb < 4; ++cb) {
            int de  = cb * 16 + l15;
            int ac0 = rb * 16 + q * 4;
#pragma unroll
            for (int r = 0; r < 4; ++r) {
                int o = (ac0 + r) * 64 + de;
                ob[o] = acc[rb][cb][r] + bias[o];
            }
        }
}

extern "C" void kernel_launch(void* const* d_in, const int* in_sizes, int n_in,
                              void* d_out, int out_size, void* d_ws, size_t ws_size,
                              hipStream_t stream) {
    const float* x    = (const float*)d_in[0];
    const float* F0   = (const float*)d_in[1];
    const float* F1   = (const float*)d_in[2];
    const float* F2   = (const float*)d_in[3];
    const float* F3   = (const float*)d_in[4];
    const float* CL   = (const float*)d_in[5];
    const float* CR   = (const float*)d_in[6];
    const float* bias = (const float*)d_in[7];
    float* out = (float*)d_out;
    unsigned short* frags = (unsigned short*)d_ws;   // 128 KB

    const int B = in_sizes[0] / 4096;   // 4096

    ht_precompute<<<256, 256, 0, stream>>>(F0, F1, F2, F3, CL, CR, frags);
    ht_main<<<B, 64, 0, stream>>>(x, frags, bias, out);
}

// Round 3
// 149.964 us; speedup vs baseline: 5.5570x; 1.0253x over previous
//
#include <hip/hip_runtime.h>
#include <hip/hip_bf16.h>

// HT layer via bf16 MFMA, one wave per batch element, 4 waves (batches) per block.
//   Y[b] = sum_p A_p(64x64) @ X_b(64x64) @ W_p(64x64) + bias
// Step A: T^T[kl][ac] = sum_ij X^T[kl][ij] * A_p^T[ij][ac]   (M=kl,N=ac,K=ij)
// Step B: Y[ac][de]  += sum_kl T[ac][kl]  * W_p[kl][de]      (M=ac,N=de,K=kl)
// mfma_f32_16x16x32_bf16 layouts (m89/m120-verified):
//   A: A[m=lane&15][k=(lane>>4)*8+j]   B: B[k=(lane>>4)*8+j][n=lane&15]
//   C/D: col=lane&15, row=(lane>>4)*4+reg
// LDS T pitch = 68 bf16 (136 B == 2 banks/row): both the b64 write pattern
// (start bank 2*(l15+q+4rb) mod 32) and the b64 read pattern
// (start bank 2*(l15+2q)+c mod 32) give exactly 4 accesses/bank = conflict-free.

typedef short bf16x8 __attribute__((ext_vector_type(8)));
typedef float f32x4  __attribute__((ext_vector_type(4)));

union Frag8 {
    bf16x8 v;
    unsigned int u4[4];
    uint2 u2[2];
};

static __device__ __forceinline__ unsigned int pkbf(float a, float b) {
    // v_cvt_pk_bf16_f32 on gfx950 (RNE), a -> low 16, b -> high 16
    __hip_bfloat162 h = __float22bfloat162_rn(float2{a, b});
    return *reinterpret_cast<unsigned int*>(&h);
}

static __device__ __forceinline__ unsigned short f2bf(float f) {
    unsigned int u = __float_as_uint(f);
    u = (u + 0x7FFFu + ((u >> 16) & 1u)) >> 16;   // RNE (software, precompute only)
    return (unsigned short)u;
}

// Precompute bf16 B-operand fragments of A_p^T and W_p into ws.
// Layout: frags[isW][p(8)][f=cb*2+ks (8)][lane(64)][j(8)] bf16, 64KB each.
// Frag element: B[k = ks*32 + (lane>>4)*8 + j][n = cb*16 + (lane&15)]
__global__ void ht_precompute(const float* __restrict__ F0, const float* __restrict__ F1,
                              const float* __restrict__ F2, const float* __restrict__ F3,
                              const float* __restrict__ CL, const float* __restrict__ CR,
                              unsigned short* __restrict__ frags) {
    int idx = blockIdx.x * blockDim.x + threadIdx.x;   // 0..65535
    int isW = idx >> 15;
    int r15 = idx & 32767;
    int p    = r15 >> 12;
    int f    = (r15 >> 9) & 7;
    int lane = (r15 >> 3) & 63;
    int j    = r15 & 7;
    int cb = f >> 1, ks = f & 1;
    int n = cb * 16 + (lane & 15);                // ac or de
    int k = ks * 32 + ((lane >> 4) & 3) * 8 + j;  // ij or kl
    const float* Fa = isW ? F2 : F0;
    const float* Fb = isW ? F3 : F1;
    const float* C  = isW ? CR : CL;
    int i1 = k >> 3, i2 = k & 7, o1 = n >> 3, o2 = n & 7;
    float acc = 0.f;
    for (int r = 0; r < 8; ++r) {
        float fa = Fa[(i1 * 8 + o1) * 8 + r];
        for (int s = 0; s < 8; ++s)
            acc += fa * Fb[(i2 * 8 + o2) * 8 + s] * C[(r * 8 + s) * 8 + p];
    }
    frags[(size_t)isW * 32768 + ((p * 8 + f) << 9) + lane * 8 + j] = f2bf(acc);
}

#define T_PITCH 68   // bf16 elements per row; 136 B = 2 banks -> conflict-free b64

__global__ __launch_bounds__(256) void ht_main(const float* __restrict__ x,
                                               const unsigned short* __restrict__ frags,
                                               const float* __restrict__ bias,
                                               float* __restrict__ out) {
    __shared__ unsigned short Tl[4 * 64 * T_PITCH];   // 34.8 KB, one slice per wave
    const int tid  = threadIdx.x;
    const int lane = tid & 63;
    const int w    = __builtin_amdgcn_readfirstlane(tid >> 6);  // wave id, scalar
    const int b    = blockIdx.x * 4 + w;                        // batch element
    unsigned short* Tw = Tl + w * (64 * T_PITCH);

    const int l15 = lane & 15;
    const int q   = lane >> 4;   // quad

    // X^T A-fragments: xf[rb][ks], element j = X^T[kl=rb*16+l15][ij=ks*32+q*8+j]
    Frag8 xf[4][2];
    const float* xb = x + ((size_t)b << 12);
#pragma unroll
    for (int rb = 0; rb < 4; ++rb)
#pragma unroll
        for (int ks = 0; ks < 2; ++ks) {
            const float* src = xb + (ks * 32 + q * 8) * 64 + rb * 16 + l15;
#pragma unroll
            for (int j = 0; j < 8; j += 2)
                xf[rb][ks].u4[j >> 1] = pkbf(src[j * 64], src[(j + 1) * 64]);
        }

    f32x4 acc[4][4];   // Y tiles: [rb over ac][cb over de]
#pragma unroll
    for (int i = 0; i < 4; ++i)
#pragma unroll
        for (int j = 0; j < 4; ++j)
            acc[i][j] = f32x4{0.f, 0.f, 0.f, 0.f};

    const unsigned short* AF = frags;          // A^T frags
    const unsigned short* WF = frags + 32768;  // W frags

#pragma unroll 1
    for (int p = 0; p < 8; ++p) {
        // ---- Step A: T^T = X^T @ A_p^T, write bf16 tiles to Tw[ac][kl]
        Frag8 af[4][2];
#pragma unroll
        for (int cb = 0; cb < 4; ++cb)
#pragma unroll
            for (int ks = 0; ks < 2; ++ks)
                af[cb][ks].v = *(const bf16x8*)(AF + (((p * 8 + cb * 2 + ks) << 9) + lane * 8));
#pragma unroll
        for (int rb = 0; rb < 4; ++rb) {       // rb: kl row-block
#pragma unroll
            for (int cb = 0; cb < 4; ++cb) {   // cb: ac col-block
                f32x4 t = f32x4{0.f, 0.f, 0.f, 0.f};
                t = __builtin_amdgcn_mfma_f32_16x16x32_bf16(xf[rb][0].v, af[cb][0].v, t, 0, 0, 0);
                t = __builtin_amdgcn_mfma_f32_16x16x32_bf16(xf[rb][1].v, af[cb][1].v, t, 0, 0, 0);
                // lane holds col ac=cb*16+l15, rows kl = rb*16+q*4+(0..3)
                int ac = cb * 16 + l15;
                int kl = rb * 16 + q * 4;
                uint2 wv;
                wv.x = pkbf(t[0], t[1]);
                wv.y = pkbf(t[2], t[3]);
                *(uint2*)(&Tw[ac * T_PITCH + kl]) = wv;   // 8B store, 8B-aligned
            }
        }
        // ---- Step B: Y += T @ W_p  (same-wave LDS RAW: compiler inserts lgkmcnt)
        Frag8 wf[4][2];
#pragma unroll
        for (int cb = 0; cb < 4; ++cb)
#pragma unroll
            for (int ks = 0; ks < 2; ++ks)
                wf[cb][ks].v = *(const bf16x8*)(WF + (((p * 8 + cb * 2 + ks) << 9) + lane * 8));
        Frag8 tf[4][2];
#pragma unroll
        for (int rb = 0; rb < 4; ++rb)
#pragma unroll
            for (int ks = 0; ks < 2; ++ks) {
                int ac = rb * 16 + l15;
                int kl = ks * 32 + q * 8;
                tf[rb][ks].u2[0] = *(const uint2*)(&Tw[ac * T_PITCH + kl]);
                tf[rb][ks].u2[1] = *(const uint2*)(&Tw[ac * T_PITCH + kl + 4]);
            }
#pragma unroll
        for (int rb = 0; rb < 4; ++rb)
#pragma unroll
            for (int cb = 0; cb < 4; ++cb) {
                acc[rb][cb] = __builtin_amdgcn_mfma_f32_16x16x32_bf16(tf[rb][0].v, wf[cb][0].v, acc[rb][cb], 0, 0, 0);
                acc[rb][cb] = __builtin_amdgcn_mfma_f32_16x16x32_bf16(tf[rb][1].v, wf[cb][1].v, acc[rb][cb], 0, 0, 0);
            }
    }

    // ---- Epilogue: bias + store (C/D: col de=cb*16+l15, rows ac=rb*16+q*4+r)
    float* ob = out + ((size_t)b << 12);
#pragma unroll
    for (int rb = 0; rb < 4; ++rb)
#pragma unroll
        for (int cb = 0; cb < 4; ++cb) {
            int de  = cb * 16 + l15;
            int ac0 = rb * 16 + q * 4;
#pragma unroll
            for (int r = 0; r < 4; ++r) {
                int o = (ac0 + r) * 64 + de;
                ob[o] = acc[rb][cb][r] + bias[o];
            }
        }
}

extern "C" void kernel_launch(void* const* d_in, const int* in_sizes, int n_in,
                              void* d_out, int out_size, void* d_ws, size_t ws_size,
                              hipStream_t stream) {
    const float* x    = (const float*)d_in[0];
    const float* F0   = (const float*)d_in[1];
    const float* F1   = (const float*)d_in[2];
    const float* F2   = (const float*)d_in[3];
    const float* F3   = (const float*)d_in[4];
    const float* CL   = (const float*)d_in[5];
    const float* CR   = (const float*)d_in[6];
    const float* bias = (const float*)d_in[7];
    float* out = (float*)d_out;
    unsigned short* frags = (unsigned short*)d_ws;   // 128 KB

    const int B = in_sizes[0] / 4096;   // 4096

    ht_precompute<<<256, 256, 0, stream>>>(F0, F1, F2, F3, CL, CR, frags);
    ht_main<<<B / 4, 256, 0, stream>>>(x, frags, bias, out);
}